// Round 2
// baseline (152.438 us; speedup 1.0000x reference)
//
#include <hip/hip_runtime.h>
#include <math.h>

// Problem: cosine similarity of x[256] vs memory[100000][256], output is
// distances * one_hot(argmax)  -> all zeros except out[argmax] = max distance.
//
// Memory-bound: 102.4 MB read, 400 KB write. Floor ~16.5 us @ 6.3 TB/s.
//
// Structure: wave-per-row (64 lanes x float4 = 1 KB row, perfectly coalesced),
// per-row dot+norm via 6-step __shfl_xor butterfly, argmax as packed u64 max
// (no atomics, no ws init needed -> immune to 0xAA poison), block partials in
// d_ws, tiny second kernel finishes the reduction and writes out[argmax].

#define EPSF 1e-8f

constexpr int D4     = 64;    // 256 floats per row = 64 float4 = one per lane
constexpr int BLOCK  = 256;   // 4 waves per block
constexpr int NBLK   = 2048;  // 8 blocks/CU * 256 CUs -> 32 waves/CU occupancy

// Monotonic unsigned key for fp32: f1 > f2  <=>  fkey(f1) > fkey(f2)
__device__ __forceinline__ unsigned fkey(float f) {
    unsigned b = __float_as_uint(f);
    return (b & 0x80000000u) ? ~b : (b | 0x80000000u);
}
__device__ __forceinline__ float funkey(unsigned u) {
    unsigned b = (u & 0x80000000u) ? (u & 0x7FFFFFFFu) : ~u;
    return __uint_as_float(b);
}

__global__ __launch_bounds__(BLOCK) void cos_argmax_main(
    const float* __restrict__ x, const float* __restrict__ mem,
    float* __restrict__ out, unsigned long long* __restrict__ part, int nrows)
{
    __shared__ unsigned long long sbest[BLOCK / 64];
    const int lane = threadIdx.x & 63;
    const int wave = threadIdx.x >> 6;

    // Coalesced zeroing of the output (harness poisons d_out with 0xAA).
    for (int i = blockIdx.x * BLOCK + threadIdx.x; i < nrows; i += gridDim.x * BLOCK)
        out[i] = 0.0f;

    // Each lane owns 4 consecutive columns of x for the whole kernel.
    const float4 xv = reinterpret_cast<const float4*>(x)[lane];
    float xn = xv.x * xv.x + xv.y * xv.y + xv.z * xv.z + xv.w * xv.w;
    #pragma unroll
    for (int off = 32; off; off >>= 1) xn += __shfl_xor(xn, off);
    const float xnorm = fmaxf(sqrtf(xn), EPSF);

    unsigned long long best = 0ull;  // smaller than any real packed key
    const int gw0     = blockIdx.x * (BLOCK / 64) + wave;
    const int wstride = gridDim.x * (BLOCK / 64);

    for (int row = gw0; row < nrows; row += wstride) {
        // size_t row base: 100000*64 float4s overflows int only at *16B, be safe
        const float4 mv = reinterpret_cast<const float4*>(mem)[(size_t)row * D4 + lane];
        float dot = mv.x * xv.x + mv.y * xv.y + mv.z * xv.z + mv.w * xv.w;
        float nrm = mv.x * mv.x + mv.y * mv.y + mv.z * mv.z + mv.w * mv.w;
        #pragma unroll
        for (int off = 32; off; off >>= 1) {
            dot += __shfl_xor(dot, off);
            nrm += __shfl_xor(nrm, off);
        }
        // All 64 lanes now hold identical dot/nrm (full butterfly).
        const float dist = dot / (fmaxf(sqrtf(nrm), EPSF) * xnorm);
        const unsigned long long p =
            ((unsigned long long)fkey(dist) << 32) | (unsigned long long)(0xFFFFFFFFu - (unsigned)row);
        best = (p > best) ? p : best;
    }

    if (lane == 0) sbest[wave] = best;
    __syncthreads();
    if (threadIdx.x == 0) {
        unsigned long long b = sbest[0];
        #pragma unroll
        for (int w = 1; w < BLOCK / 64; ++w) b = (sbest[w] > b) ? sbest[w] : b;
        part[blockIdx.x] = b;
    }
}

__global__ __launch_bounds__(BLOCK) void cos_argmax_final(
    const unsigned long long* __restrict__ part, float* __restrict__ out, int nparts)
{
    __shared__ unsigned long long sred[BLOCK];
    unsigned long long best = 0ull;
    for (int i = threadIdx.x; i < nparts; i += BLOCK) {
        const unsigned long long p = part[i];
        best = (p > best) ? p : best;
    }
    sred[threadIdx.x] = best;
    __syncthreads();
    // Tree-reduce 256 -> 1 in LDS (kernel is tiny; simplicity > cleverness).
    for (int s = BLOCK / 2; s > 0; s >>= 1) {
        if (threadIdx.x < s) {
            const unsigned long long o = sred[threadIdx.x + s];
            if (o > sred[threadIdx.x]) sred[threadIdx.x] = o;
        }
        __syncthreads();
    }
    if (threadIdx.x == 0) {
        const unsigned long long b = sred[0];
        const unsigned idx = 0xFFFFFFFFu - (unsigned)(b & 0xFFFFFFFFull);
        out[idx] = funkey((unsigned)(b >> 32));
    }
}

extern "C" void kernel_launch(void* const* d_in, const int* in_sizes, int n_in,
                              void* d_out, int out_size, void* d_ws, size_t ws_size,
                              hipStream_t stream) {
    const float* x   = (const float*)d_in[0];
    const float* mem = (const float*)d_in[1];
    float* out       = (float*)d_out;
    const int nrows  = in_sizes[1] / 256;   // 100000
    unsigned long long* part = (unsigned long long*)d_ws;  // NBLK * 8 B = 16 KB

    cos_argmax_main<<<NBLK, BLOCK, 0, stream>>>(x, mem, out, part, nrows);
    cos_argmax_final<<<1, BLOCK, 0, stream>>>(part, out, NBLK);
}